// Round 1
// 115.679 us; speedup vs baseline: 1.0047x; 1.0047x over previous
//
#include <hip/hip_runtime.h>
#include <hip/hip_bf16.h>
#include <math.h>

#define HS 64
#define NE 128
#define TSEQ 2048

typedef short s8v __attribute__((ext_vector_type(8)));   // 8 bf16 (4 VGPRs) MFMA A/B frag
typedef float f4v __attribute__((ext_vector_type(4)));   // 4 fp32 MFMA C/D frag

__device__ __forceinline__ unsigned short f2bf(float f) {
    unsigned int u = __float_as_uint(f);
    u += 0x7FFFu + ((u >> 16) & 1u);   // RNE (no NaN inputs here)
    return (unsigned short)(u >> 16);
}

__device__ __forceinline__ unsigned int pkbf(float a, float b) {
    union { __hip_bfloat162 h; unsigned int u; } cv;
    cv.h = __float22bfloat162_rn(make_float2(a, b));
    return cv.u;
}

__device__ __forceinline__ s8v mk_s8v(unsigned int a, unsigned int b,
                                      unsigned int c, unsigned int d) {
    union { unsigned int u[4]; s8v v; } cv;
    cv.u[0] = a; cv.u[1] = b; cv.u[2] = c; cv.u[3] = d;
    return cv.v;
}

// raw v_exp_f32 (2^x). exp2f without -ffast-math is an OCML call — critical-path killer.
__device__ __forceinline__ float fexp2(float x) {
    float r;
    asm("v_exp_f32 %0, %1" : "=v"(r) : "v"(x));
    return r;
}

// async global->LDS, 16B per lane (dest = wave-uniform base + lane*16).
__device__ __forceinline__ void glds16(const unsigned short* g, unsigned short* l) {
    __builtin_amdgcn_global_load_lds(
        (const __attribute__((address_space(1))) unsigned int*)g,
        (__attribute__((address_space(3))) unsigned int*)l,
        16, 0, 0);
}

// ---------------- W -> bf16, transposed wt[mat][n][k], q pre-scaled ----------------
__global__ __launch_bounds__(256) void wconv(
    const float* __restrict__ Wq, const float* __restrict__ Wk,
    const float* __restrict__ Wv, unsigned short* __restrict__ wt)
{
    const int o0 = (blockIdx.x * 256 + threadIdx.x) * 2;   // 24576 elems total
    const int mat = o0 >> 13;
    const int n = (o0 >> 7) & 63;
    const int k = o0 & 127;        // even
    const float* W = (mat == 0) ? Wq : (mat == 1) ? Wk : Wv;
    const float s = (mat == 0) ? 0.18033688f : 1.0f;   // 64^-0.5 * log2(e)
    unsigned int lo = f2bf(W[k * HS + n] * s);
    unsigned int hi = f2bf(W[(k + 1) * HS + n] * s);
    *(unsigned int*)(wt + o0) = lo | (hi << 16);
}

// ---------------- QKV projection (unchanged: bf16 MFMA, W in LDS) ----------------
__global__ __launch_bounds__(256) void qkv(
    const float* __restrict__ x, const unsigned short* __restrict__ wt,
    const float* __restrict__ bq, const float* __restrict__ bk,
    const float* __restrict__ bv,
    unsigned short* __restrict__ qo, unsigned short* __restrict__ ko,
    unsigned short* __restrict__ vt)
{
    __shared__ __align__(16) unsigned short Ws[192 * 136];  // 51 KB; reused for transpose

    const int tid = threadIdx.x;
    const int w = tid >> 6;
    const int lane = tid & 63;
    const int quad = lane >> 4;
    const int li = lane & 15;
    const size_t blk0 = (size_t)blockIdx.x * 64;
    const size_t row0w = blk0 + (size_t)w * 16;

#pragma unroll
    for (int p = 0; p < 12; ++p) {
        const int idx = p * 256 + tid;
        const int n = idx >> 4;
        const int c = idx & 15;
        s8v d = *(const s8v*)(wt + idx * 8);
        *(s8v*)&Ws[n * 136 + c * 8] = d;
    }

    s8v a[4];
    const float* xr = x + (row0w + li) * NE + quad * 8;
#pragma unroll
    for (int ks = 0; ks < 4; ++ks) {
        float4 f0 = *(const float4*)(xr + ks * 32);
        float4 f1 = *(const float4*)(xr + ks * 32 + 4);
        a[ks] = mk_s8v(pkbf(f0.x, f0.y), pkbf(f0.z, f0.w),
                       pkbf(f1.x, f1.y), pkbf(f1.z, f1.w));
    }

    __syncthreads();

    f4v acc[12];
#pragma unroll
    for (int nt = 0; nt < 12; ++nt) acc[nt] = (f4v){0.f, 0.f, 0.f, 0.f};

#pragma unroll
    for (int nt = 0; nt < 12; ++nt) {
        const unsigned short* wr = &Ws[(nt * 16 + li) * 136 + quad * 8];
#pragma unroll
        for (int ks = 0; ks < 4; ++ks) {
            s8v bfr = *(const s8v*)(wr + ks * 32);
            acc[nt] = __builtin_amdgcn_mfma_f32_16x16x32_bf16(a[ks], bfr, acc[nt], 0, 0, 0);
        }
    }

    const size_t bidx = row0w >> 11;
    const size_t trow0 = row0w & 2047;
#pragma unroll
    for (int nt = 0; nt < 4; ++nt) {
        const float bias = bv[nt * 16 + li];
        unsigned int lo = pkbf(acc[nt + 8][0] + bias, acc[nt + 8][1] + bias);
        unsigned int hi = pkbf(acc[nt + 8][2] + bias, acc[nt + 8][3] + bias);
        *(uint2*)(vt + (bidx * HS + nt * 16 + li) * TSEQ + trow0 + quad * 4) =
            make_uint2(lo, hi);
    }

    __syncthreads();

    float* Qt = (float*)Ws;            // [64][68]
    float* Kt = Qt + 64 * 68;
    const float sq = 0.18033688f;
    const int lrow0 = w * 16 + quad * 4;
#pragma unroll
    for (int nt = 0; nt < 4; ++nt) {
        const int col = nt * 16 + li;
        const float bq_ = bq[col] * sq;
        const float bk_ = bk[col];
#pragma unroll
        for (int r = 0; r < 4; ++r) {
            Qt[(lrow0 + r) * 68 + col] = acc[nt][r] + bq_;
            Kt[(lrow0 + r) * 68 + col] = acc[nt + 4][r] + bk_;
        }
    }

    __syncthreads();

    const int row = tid >> 2;
    const int seg = tid & 3;
    {
        const float* src = &Qt[row * 68 + seg * 16];
        float4 f0 = *(const float4*)src;
        float4 f1 = *(const float4*)(src + 4);
        float4 f2 = *(const float4*)(src + 8);
        float4 f3 = *(const float4*)(src + 12);
        s8v d0 = mk_s8v(pkbf(f0.x, f0.y), pkbf(f0.z, f0.w), pkbf(f1.x, f1.y), pkbf(f1.z, f1.w));
        s8v d1 = mk_s8v(pkbf(f2.x, f2.y), pkbf(f2.z, f2.w), pkbf(f3.x, f3.y), pkbf(f3.z, f3.w));
        unsigned short* dst = qo + (blk0 + row) * HS + seg * 16;
        *(s8v*)dst = d0;
        *(s8v*)(dst + 8) = d1;
    }
    {
        const float* src = &Kt[row * 68 + seg * 16];
        float4 f0 = *(const float4*)src;
        float4 f1 = *(const float4*)(src + 4);
        float4 f2 = *(const float4*)(src + 8);
        float4 f3 = *(const float4*)(src + 12);
        s8v d0 = mk_s8v(pkbf(f0.x, f0.y), pkbf(f0.z, f0.w), pkbf(f1.x, f1.y), pkbf(f1.z, f1.w));
        s8v d1 = mk_s8v(pkbf(f2.x, f2.y), pkbf(f2.z, f2.w), pkbf(f3.x, f3.y), pkbf(f3.z, f3.w));
        unsigned short* dst = ko + (blk0 + row) * HS + seg * 16;
        *(s8v*)dst = d0;
        *(s8v*)(dst + 8) = d1;
    }
}

// ---------------- Flash attention: Q128 blocks x K64 tiles ----------------
// Each 256-thread block owns a 128-row Q block (two 16-row groups per wave)
// and runs both groups against the same staged K/V 64-tile: halves tile
// iterations (8448 -> 4352), staged bytes, and barrier count vs the Q64
// version. Chunks of <=8 key-tiles for balance; nc>1 chunks write fp32
// O-partials + lsum (no-max exp2 softmax => chunks additive).
// 640 blocks = 16 batches * 40 chunks; XCD-swizzled (2 batches per XCD).
__device__ __forceinline__ void attn_tile_group(
    const unsigned short* Kc, const unsigned short* Vc,
    char* pbse, int lane, int quad, int li, int swz0, int swz1,
    int tl, int dg, int qrow, s8v qf0, s8v qf1, f4v* c_o, float& lsum)
{
    float pr[4][4];
    float rs = 0.f;
#pragma unroll
    for (int kt = 0; kt < 4; ++kt) {
        const unsigned short* krow = Kc + (kt * 16 + li) * 64;
        s8v k0 = *(const s8v*)(krow + swz0);
        s8v k1 = *(const s8v*)(krow + swz1);
        f4v cst = (f4v){0.f, 0.f, 0.f, 0.f};
        __builtin_amdgcn_s_setprio(1);
        cst = __builtin_amdgcn_mfma_f32_16x16x32_bf16(k0, qf0, cst, 0, 0, 0);
        cst = __builtin_amdgcn_mfma_f32_16x16x32_bf16(k1, qf1, cst, 0, 0, 0);
        __builtin_amdgcn_s_setprio(0);
        if (tl == dg) {
            const int key0 = (tl << 6) + kt * 16 + quad * 4;
#pragma unroll
            for (int rr = 0; rr < 4; ++rr)
                if (key0 + rr > qrow) cst[rr] = -INFINITY;
        }
#pragma unroll
        for (int rr = 0; rr < 4; ++rr) {
            pr[kt][rr] = fexp2(cst[rr]);
            rs += pr[kt][rr];
        }
    }
    lsum += rs;

    // P -> LDS (granule-transposed, conflict-free; wave-private buffer)
#pragma unroll
    for (int kt = 0; kt < 4; ++kt) {
        *(uint2*)(pbse + (kt * 2 + (quad >> 1)) * 256 + li * 16 + (quad & 1) * 8) =
            make_uint2(pkbf(pr[kt][0], pr[kt][1]), pkbf(pr[kt][2], pr[kt][3]));
    }
    s8v pf0 = *(const s8v*)(pbse + lane * 16);
    s8v pf1 = *(const s8v*)(pbse + 1024 + lane * 16);

    // O^T += V^T . P^T
#pragma unroll
    for (int f = 0; f < 4; ++f) {
        const unsigned short* vrow = Vc + (f * 16 + li) * 64;
        s8v v0 = *(const s8v*)(vrow + swz0);
        s8v v1 = *(const s8v*)(vrow + swz1);
        __builtin_amdgcn_s_setprio(1);
        c_o[f] = __builtin_amdgcn_mfma_f32_16x16x32_bf16(v0, pf0, c_o[f], 0, 0, 0);
        c_o[f] = __builtin_amdgcn_mfma_f32_16x16x32_bf16(v1, pf1, c_o[f], 0, 0, 0);
        __builtin_amdgcn_s_setprio(0);
    }
}

__global__ __launch_bounds__(256) void attn_main(
    const unsigned short* __restrict__ qbf,
    const unsigned short* __restrict__ kb,
    const unsigned short* __restrict__ vtb,
    float* __restrict__ out, float* __restrict__ pbuf, float* __restrict__ lsbuf)
{
    __shared__ unsigned short Ks[2][64 * 64];
    __shared__ unsigned short Vs[2][64 * 64];
    __shared__ __align__(16) unsigned short Ps[4][1024];   // per-wave, reused per group

    const int tid = threadIdx.x;
    const int w = tid >> 6;
    const int lane = tid & 63;
    const int quad = lane >> 4;
    const int li = lane & 15;

    // XCD swizzle: blocks round-robin XCDs by id&7 -> give each XCD 2 whole
    // batches so its L2 (4 MiB) holds their K/V (1 MiB). Big chunks first.
    const int id = blockIdx.x;
    const int xcd = id & 7;
    const int j = id >> 3;                 // 0..79 within XCD
    const int b = xcd * 2 + (j >= 40);
    const int jj = (j >= 40) ? j - 40 : j;
    const int u = 39 - jj;                 // big chunks dispatched first
    int qb, c, nc;
    if (u < 4)       { qb = u;                    c = 0;             nc = 1; }
    else if (u < 12) { qb = 4 + ((u - 4) >> 1);   c = (u - 4) & 1;   nc = 2; }
    else if (u < 24) { qb = 8 + (u - 12) / 3;     c = (u - 12) % 3;  nc = 3; }
    else             { qb = 12 + ((u - 24) >> 2); c = (u - 24) & 3;  nc = 4; }
    const int tb = c * 8;
    const int ntile = 2 * qb + 2;
    const int te = (tb + 8 < ntile) ? tb + 8 : ntile;

    const size_t base = (size_t)b * TSEQ;
    const int t0 = qb << 7;
    const int qrow0 = t0 + w * 16 + li;        // group A: rows 0..63 of block
    const int qrow1 = qrow0 + 64;              // group B: rows 64..127
    const int d0 = 2 * qb;                     // diag key-tile for group A
    const int d1 = 2 * qb + 1;                 // diag key-tile for group B

    // Q B-frags for both groups (scale*log2e pre-folded)
    const unsigned short* qrp0 = qbf + (base + qrow0) * HS + quad * 8;
    s8v qA0 = *(const s8v*)qrp0;
    s8v qA1 = *(const s8v*)(qrp0 + 32);
    const unsigned short* qrp1 = qrp0 + 64 * HS;
    s8v qB0 = *(const s8v*)qrp1;
    s8v qB1 = *(const s8v*)(qrp1 + 32);

    // staging geometry (verified): wave w stages K/V rows [w*8,w*8+8) and +32
    const int rA = w * 8 + (lane >> 3);
    const int csw = (lane & 7) ^ (rA & 7);
    const unsigned short* kgA = kb + (base + rA) * HS + csw * 8;
    const unsigned short* kgB = kgA + 32 * HS;
    const unsigned short* vgA = vtb + ((size_t)b * HS + rA) * TSEQ + csw * 8;
    const unsigned short* vgB = vgA + 32 * TSEQ;
    const int ldsA = w * 512 + lane * 8;
    const int ldsB = 2048 + w * 512 + lane * 8;

    // prologue: stage tile tb -> buf 0
    glds16(kgA + (size_t)tb * 4096, &Ks[0][ldsA]);
    glds16(kgB + (size_t)tb * 4096, &Ks[0][ldsB]);
    glds16(vgA + (size_t)tb * 64,   &Vs[0][ldsA]);
    glds16(vgB + (size_t)tb * 64,   &Vs[0][ldsB]);

    f4v c_oA[4], c_oB[4];
#pragma unroll
    for (int f = 0; f < 4; ++f) {
        c_oA[f] = (f4v){0.f, 0.f, 0.f, 0.f};
        c_oB[f] = (f4v){0.f, 0.f, 0.f, 0.f};
    }
    float lsA = 0.f, lsB = 0.f;

    char* pbse = (char*)&Ps[w][0];
    const int swz0 = (quad ^ (li & 7)) * 8;
    const int swz1 = ((4 + quad) ^ (li & 7)) * 8;

    __syncthreads();

    for (int tl = tb; tl < te; ++tl) {
        const int bi = (tl - tb) & 1;
        if (tl + 1 < te) {
            const int nb = bi ^ 1;
            glds16(kgA + (size_t)(tl + 1) * 4096, &Ks[nb][ldsA]);
            glds16(kgB + (size_t)(tl + 1) * 4096, &Ks[nb][ldsB]);
            glds16(vgA + (size_t)(tl + 1) * 64,   &Vs[nb][ldsA]);
            glds16(vgB + (size_t)(tl + 1) * 64,   &Vs[nb][ldsB]);
        }
        const unsigned short* Kc = &Ks[bi][0];
        const unsigned short* Vc = &Vs[bi][0];

        // group A (skip tiles entirely above its diagonal — block-uniform)
        if (tl <= d0)
            attn_tile_group(Kc, Vc, pbse, lane, quad, li, swz0, swz1,
                            tl, d0, qrow0, qA0, qA1, c_oA, lsA);
        // group B (always in range: tl <= 2qb+1 = d1)
        attn_tile_group(Kc, Vc, pbse, lane, quad, li, swz0, swz1,
                        tl, d1, qrow1, qB0, qB1, c_oB, lsB);

        __syncthreads();   // buf[bi] reads done; prefetch drained
    }

    // per-row lsum (sum the 4 quads)
    lsA += __shfl_xor(lsA, 16);
    lsA += __shfl_xor(lsA, 32);
    lsB += __shfl_xor(lsB, 16);
    lsB += __shfl_xor(lsB, 32);

    if (nc == 1) {
        const float invA = 1.0f / lsA;
        float* orowA = out + (base + qrow0) * HS + quad * 4;
#pragma unroll
        for (int f = 0; f < 4; ++f) {
            f4v res = c_oA[f];
            res[0] *= invA; res[1] *= invA; res[2] *= invA; res[3] *= invA;
            *(f4v*)(orowA + f * 16) = res;
        }
        const float invB = 1.0f / lsB;
        float* orowB = out + (base + qrow1) * HS + quad * 4;
#pragma unroll
        for (int f = 0; f < 4; ++f) {
            f4v res = c_oB[f];
            res[0] *= invB; res[1] *= invB; res[2] *= invB; res[3] *= invB;
            *(f4v*)(orowB + f * 16) = res;
        }
    } else {
        const int local = (qb < 8)  ? (qb - 4) * 2 + c
                        : (qb < 12) ? 8 + (qb - 8) * 3 + c
                                    : 20 + (qb - 12) * 4 + c;
        const int pidx = b * 36 + local;
        float* pc = pbuf + (size_t)pidx * 8192 + (w * 16 + li) * 64;
#pragma unroll
        for (int f = 0; f < 4; ++f)
            *(f4v*)(pc + f * 16 + quad * 4) = c_oA[f];
        float* pc1 = pc + 64 * 64;
#pragma unroll
        for (int f = 0; f < 4; ++f)
            *(f4v*)(pc1 + f * 16 + quad * 4) = c_oB[f];
        if (quad == 0) {
            lsbuf[(size_t)pidx * 128 + w * 16 + li] = lsA;
            lsbuf[(size_t)pidx * 128 + 64 + w * 16 + li] = lsB;
        }
    }
}

// ---------------- Partial combine + normalize (qb >= 4) ----------------
__global__ __launch_bounds__(256) void attn_reduce(
    const float* __restrict__ pbuf, const float* __restrict__ lsbuf,
    float* __restrict__ out)
{
    const int g = blockIdx.x;            // 192 = 16 batches * 12 q128-blocks
    const int b = g / 12;
    const int r = g - b * 12;
    int qb, lbase, nc;
    if (r < 4)      { qb = 4 + r;        lbase = 2 * r;            nc = 2; }
    else if (r < 8) { qb = 8 + (r - 4);  lbase = 8 + 3 * (r - 4);  nc = 3; }
    else            { qb = 12 + (r - 8); lbase = 20 + 4 * (r - 8); nc = 4; }
    const int pidx0 = b * 36 + lbase;

    const int tid = threadIdx.x;
    const int row = tid >> 1;            // 0..127
    const int seg = tid & 1;             // 32-float half of the 64-wide row

    float4 acc[8];
#pragma unroll
    for (int j = 0; j < 8; ++j) acc[j] = make_float4(0.f, 0.f, 0.f, 0.f);
    float ls = 0.f;

    for (int cc = 0; cc < nc; ++cc) {
        const float* pc = pbuf + (size_t)(pidx0 + cc) * 8192 + row * 64 + seg * 32;
#pragma unroll
        for (int j = 0; j < 8; ++j) {
            float4 v = *(const float4*)(pc + j * 4);
            acc[j].x += v.x; acc[j].y += v.y; acc[j].z += v.z; acc[j].w += v.w;
        }
        ls += lsbuf[(size_t)(pidx0 + cc) * 128 + row];
    }
    const float inv = 1.0f / ls;
    float* orow = out + ((size_t)b * TSEQ + (qb << 7) + row) * HS + seg * 32;
#pragma unroll
    for (int j = 0; j < 8; ++j) {
        *(float4*)(orow + j * 4) = make_float4(acc[j].x * inv, acc[j].y * inv,
                                               acc[j].z * inv, acc[j].w * inv);
    }
}

extern "C" void kernel_launch(void* const* d_in, const int* in_sizes, int n_in,
                              void* d_out, int out_size, void* d_ws, size_t ws_size,
                              hipStream_t stream) {
    const float* x  = (const float*)d_in[0];
    const float* Wk = (const float*)d_in[1];
    const float* bk = (const float*)d_in[2];
    const float* Wq = (const float*)d_in[3];
    const float* bq = (const float*)d_in[4];
    const float* Wv = (const float*)d_in[5];
    const float* bv = (const float*)d_in[6];
    float* outp = (float*)d_out;

    const size_t elems = (size_t)16 * TSEQ * HS;  // 2M per tensor
    unsigned short* qbuf = (unsigned short*)d_ws;
    unsigned short* kbuf = qbuf + elems;
    unsigned short* vbuf = kbuf + elems;          // transposed [b][dim][t]
    unsigned short* wtb  = vbuf + elems;          // [3][64][128] bf16
    float* pbuf  = (float*)(wtb + 32768);         // [576][128][64] fp32 partials
    float* lsbuf = pbuf + (size_t)576 * 8192;     // [576][128] lsums

    wconv<<<48, 256, 0, stream>>>(Wq, Wk, Wv, wtb);
    qkv<<<512, 256, 0, stream>>>(x, wtb, bq, bk, bv, qbuf, kbuf, vbuf);
    attn_main<<<640, 256, 0, stream>>>(qbuf, kbuf, vbuf, outp, pbuf, lsbuf);
    attn_reduce<<<192, 256, 0, stream>>>(pbuf, lsbuf, outp);
}